// Round 2
// baseline (2452.924 us; speedup 1.0000x reference)
//
#include <hip/hip_runtime.h>
#include <math.h>
#include <stdint.h>

#define H 128
#define NFACT 100000
#define NCOMP 2000
#define NEDGE 800000
#define BGRAPH 256
#define DF 1536
#define DC 27
#define LEPS 1e-5f

using bf16x8 = __attribute__((ext_vector_type(8))) __bf16;
using f32x4  = __attribute__((ext_vector_type(4))) float;
static_assert(sizeof(bf16x8) == 16, "bf16x8 must be 16B");

__device__ __forceinline__ float sigmoidf(float x) { return 1.0f / (1.0f + __expf(-x)); }

// fp32 -> bf16 hi/lo split (native casts; RTNE on gfx950)
__device__ __forceinline__ void split2(float x, __bf16& h, __bf16& l) {
    h = (__bf16)x;
    l = (__bf16)(x - (float)h);
}
__device__ __forceinline__ f32x4 mfma16(bf16x8 a, bf16x8 b, f32x4 c) {
    return __builtin_amdgcn_mfma_f32_16x16x32_bf16(a, b, c, 0, 0, 0);
}

__device__ __forceinline__ int lowerb(const int* __restrict__ a, int n, int v) {
    int lo = 0, hi = n;
    while (lo < hi) { int mid = (lo + hi) >> 1; if (a[mid] < v) lo = mid + 1; else hi = mid; }
    return lo;
}

// ---------------- runtime detection of primary_mask storage (u8 bool vs i32) --------
__global__ void mask_detect(const unsigned char* __restrict__ m, int n, int* __restrict__ flag) {
    __shared__ int f;
    if (threadIdx.x == 0) f = 0;
    __syncthreads();
    int local = 0;
    for (int i = threadIdx.x; i < n; i += blockDim.x)
        if ((i & 3) && m[i]) local = 1;
    if (local) atomicOr(&f, 1);
    __syncthreads();
    if (threadIdx.x == 0) *flag = f;
}

// ---------------- CSR build (both edge sets in one kernel each) ----------------------
__global__ __launch_bounds__(256)
void hist_all(const int* __restrict__ dst_fc, const int* __restrict__ dst_cf,
              int* __restrict__ cur_fc, int* __restrict__ cur_cf) {
    int e = blockIdx.x * 256 + threadIdx.x;
    if (e < NEDGE) {
        atomicAdd(&cur_fc[dst_fc[e]], 1);
    } else {
        e -= NEDGE;
        if (e < NEDGE) atomicAdd(&cur_cf[dst_cf[e]], 1);
    }
}

// exclusive scan; block 0 -> fc(NCOMP), block 1 -> cf(NFACT). Also writes cur=off.
__global__ __launch_bounds__(1024)
void scan2(int* __restrict__ cur_fc, int* __restrict__ off_fc,
           int* __restrict__ cur_cf, int* __restrict__ off_cf) {
    __shared__ int part[1024];
    int* cnt; int* off; int n;
    if (blockIdx.x == 0) { cnt = cur_fc; off = off_fc; n = NCOMP; }
    else                 { cnt = cur_cf; off = off_cf; n = NFACT; }
    int t = threadIdx.x;
    int chunk = (n + 1023) >> 10;
    int lo = t * chunk, hi = lo + chunk; if (hi > n) hi = n; if (lo > n) lo = n;
    int s = 0;
    for (int i = lo; i < hi; ++i) s += cnt[i];
    part[t] = s;
    __syncthreads();
    for (int o = 1; o < 1024; o <<= 1) {
        int v = (t >= o) ? part[t - o] : 0;
        __syncthreads();
        part[t] += v;
        __syncthreads();
    }
    int run = (t == 0) ? 0 : part[t - 1];
    for (int i = lo; i < hi; ++i) {
        int c = cnt[i];
        off[i] = run;
        cnt[i] = run;      // cur = off copy for scatter
        run += c;
    }
    if (t == 1023) off[n] = part[1023];
}

__global__ __launch_bounds__(256)
void scatter_all(const int* __restrict__ src_fc, const int* __restrict__ dst_fc,
                 const float* __restrict__ ea_fc,
                 const int* __restrict__ src_cf, const int* __restrict__ dst_cf,
                 const float* __restrict__ ea_cf,
                 const float* __restrict__ wmix, const float* __restrict__ bmix,
                 int* __restrict__ cur_fc, int* __restrict__ cur_cf,
                 int* __restrict__ ssrc_fc, float* __restrict__ swt_fc,
                 int* __restrict__ ssrc_cf, float* __restrict__ swt_cf) {
    int e = blockIdx.x * 256 + threadIdx.x;
    float wm = wmix[0], bm = bmix[0];
    if (e < NEDGE) {
        int d = dst_fc[e];
        int pos = atomicAdd(&cur_fc[d], 1);
        ssrc_fc[pos] = src_fc[e];
        swt_fc[pos] = sigmoidf(ea_fc[e] * wm + bm);
    } else {
        e -= NEDGE;
        if (e < NEDGE) {
            int d = dst_cf[e];
            int pos = atomicAdd(&cur_cf[d], 1);
            ssrc_cf[pos] = src_cf[e];
            swt_cf[pos] = sigmoidf(ea_cf[e] * wm + bm);
        }
    }
}

// ---------------- gather: company side (2000 rows, deg~400), 4 edge slots -----------
__global__ __launch_bounds__(512)
void gather_comp(const int* __restrict__ off, const int* __restrict__ ssrc,
                 const float* __restrict__ swt, const float* __restrict__ feat,
                 float* __restrict__ out) {
    __shared__ float tmp[3][128];
    int d = blockIdx.x;
    int lo = off[d], hi = off[d + 1];
    int h = threadIdx.x & 127;
    int slot = threadIdx.x >> 7;          // 4 edge slots
    float acc = 0.f;
    for (int j = lo + slot; j < hi; j += 4)
        acc += swt[j] * feat[(size_t)ssrc[j] * H + h];
    if (slot > 0) tmp[slot - 1][h] = acc;
    __syncthreads();
    if (slot == 0)
        out[(size_t)d * H + h] = acc + tmp[0][h] + tmp[1][h] + tmp[2][h];
}

// ---------------- gather: fact side (100000 rows, deg~8, src table L2-resident) ------
__global__ __launch_bounds__(256)
void gather_fact(const int* __restrict__ off, const int* __restrict__ ssrc,
                 const float* __restrict__ swt, const float* __restrict__ feat,
                 float* __restrict__ out) {
    int d = blockIdx.x * 2 + (threadIdx.x >> 7);
    if (d >= NFACT) return;
    int h = threadIdx.x & 127;
    int lo = off[d], hi = off[d + 1];
    float acc = 0.f;
    for (int j = lo; j < hi; ++j)
        acc += swt[j] * feat[(size_t)ssrc[j] * H + h];
    out[(size_t)d * H + h] = acc;
}

// ---------------- preconvert weights -> fragment-ordered bf16 hi/lo ------------------
// elem layout (verified round 1): base = (((t*8 + nsub)*2)*64 + ln)*8 + i ; lo at +512
// holding W[nsub*16 + (lane&15)][t*32 + (lane>>4)*8 + i]
__device__ __forceinline__ void conv_one(const float* __restrict__ W, int K, int idx,
                                         __bf16* __restrict__ out) {
    int n = idx / K, k = idx - n * K;
    int t = k >> 5, rem = k & 31, sub = rem >> 3, i = rem & 7;
    int nsub = n >> 4, ln = (sub << 4) | (n & 15);
    __bf16 h, l; split2(W[idx], h, l);
    size_t base = (((size_t)(t * 8 + nsub) * 2) * 64 + ln) * 8 + i;
    out[base] = h;
    out[base + 512] = l;
}

__global__ __launch_bounds__(256)
void conv_all(const float* __restrict__ W_in_f,
              const float* __restrict__ Wroot0, const float* __restrict__ Wroot1,
              __bf16* __restrict__ WencF, __bf16* __restrict__ Wr0F,
              __bf16* __restrict__ Wr1F) {
    int e = blockIdx.x * 256 + threadIdx.x;
    const int T1 = 128 * DF;          // 196608
    const int T2 = T1 + 128 * 128;    // +16384
    const int T3 = T2 + 128 * 128;
    if (e < T1)      conv_one(W_in_f, DF, e, WencF);
    else if (e < T2) conv_one(Wroot0, 128, e - T1, Wr0F);
    else if (e < T3) conv_one(Wroot1, 128, e - T2, Wr1F);
}

// ---------------- unified MFMA GEMM: out = LN(relu(A@W^T + bias [+ Cinit])) ----------
// A [M,K] fp32 streamed+split in-tile; W frag-ordered bf16 hi/lo; 128x128 tile,
// 4 waves x (mi=8, nj=2); fused bias+ReLU+LayerNorm epilogue. Cinit nullable [M,H].
__global__ __launch_bounds__(256)
void gemm128_mfma(const float* __restrict__ A, const __bf16* __restrict__ Wf,
                  const float* __restrict__ Cinit,
                  const float* __restrict__ bias, const float* __restrict__ gamma,
                  const float* __restrict__ beta, float* __restrict__ out,
                  int M, int K) {
    __shared__ __bf16 Ahi[128][40];   // stride 80B: b128 access conflict-optimal
    __shared__ __bf16 Alo[128][40];
    __shared__ float red[128][8];

    const int tid = threadIdx.x;
    const int lane = tid & 63;
    const int w = tid >> 6;           // wave = 32-col strip
    const int m0 = blockIdx.x * 128;
    const int fr = lane & 15;
    const int fq = lane >> 4;

    const int srow = tid & 127;              // staging row
    const int scol = (tid >> 7) * 16;        // col half 0/16
    int arow = m0 + srow; if (arow >= M) arow = M - 1;
    const float* __restrict__ ap = A + (size_t)arow * K + scol;

    f32x4 acc[8][2];
#pragma unroll
    for (int mi = 0; mi < 8; ++mi)
#pragma unroll
        for (int nj = 0; nj < 2; ++nj)
#pragma unroll
            for (int e = 0; e < 4; ++e) acc[mi][nj][e] = 0.f;

    const int NT = K >> 5;
    float4 pf0 = *(const float4*)(ap);
    float4 pf1 = *(const float4*)(ap + 4);
    float4 pf2 = *(const float4*)(ap + 8);
    float4 pf3 = *(const float4*)(ap + 12);

    for (int t = 0; t < NT; ++t) {
        bf16x8 hv0, hv1, lv0, lv1;
        {
            float xs[16] = {pf0.x, pf0.y, pf0.z, pf0.w, pf1.x, pf1.y, pf1.z, pf1.w,
                            pf2.x, pf2.y, pf2.z, pf2.w, pf3.x, pf3.y, pf3.z, pf3.w};
#pragma unroll
            for (int j = 0; j < 8; ++j)  { __bf16 h, l; split2(xs[j], h, l);     hv0[j] = h; lv0[j] = l; }
#pragma unroll
            for (int j = 0; j < 8; ++j)  { __bf16 h, l; split2(xs[8 + j], h, l); hv1[j] = h; lv1[j] = l; }
        }
        __syncthreads();                 // prior iter's frag reads complete
        *(bf16x8*)&Ahi[srow][scol]     = hv0;
        *(bf16x8*)&Ahi[srow][scol + 8] = hv1;
        *(bf16x8*)&Alo[srow][scol]     = lv0;
        *(bf16x8*)&Alo[srow][scol + 8] = lv1;
        __syncthreads();

        if (t + 1 < NT) {                // prefetch next X tile under MFMA phase
            const float* np = ap + (size_t)(t + 1) * 32;
            pf0 = *(const float4*)(np);
            pf1 = *(const float4*)(np + 4);
            pf2 = *(const float4*)(np + 8);
            pf3 = *(const float4*)(np + 12);
        }

        const __bf16* wt = Wf + (size_t)t * 8192 + (size_t)(2 * w) * 1024 + lane * 8;
        bf16x8 bh0 = *(const bf16x8*)(wt);
        bf16x8 bl0 = *(const bf16x8*)(wt + 512);
        bf16x8 bh1 = *(const bf16x8*)(wt + 1024);
        bf16x8 bl1 = *(const bf16x8*)(wt + 1536);

        bf16x8 ah[8], al[8];
#pragma unroll
        for (int mi = 0; mi < 8; ++mi) {
            ah[mi] = *(const bf16x8*)&Ahi[mi * 16 + fr][fq * 8];
            al[mi] = *(const bf16x8*)&Alo[mi * 16 + fr][fq * 8];
        }
#pragma unroll
        for (int mi = 0; mi < 8; ++mi) {
            acc[mi][0] = mfma16(ah[mi], bh0, acc[mi][0]);
            acc[mi][0] = mfma16(al[mi], bh0, acc[mi][0]);
            acc[mi][0] = mfma16(ah[mi], bl0, acc[mi][0]);
            acc[mi][1] = mfma16(ah[mi], bh1, acc[mi][1]);
            acc[mi][1] = mfma16(al[mi], bh1, acc[mi][1]);
            acc[mi][1] = mfma16(ah[mi], bl1, acc[mi][1]);
        }
    }

    // -------- epilogue: [+Cinit] + bias + relu + LayerNorm over 128-col rows ---------
    const int col0 = w * 32 + fr;
    const int col1 = col0 + 16;
    const float bi0 = bias[col0], bi1 = bias[col1];
    const float g0 = gamma[col0], g1 = gamma[col1];
    const float be0 = beta[col0], be1 = beta[col1];

    float s[8][4], q[8][4];
#pragma unroll
    for (int mi = 0; mi < 8; ++mi)
#pragma unroll
        for (int r = 0; r < 4; ++r) {
            int row = mi * 16 + fq * 4 + r;
            int grow = m0 + row; if (grow >= M) grow = M - 1;   // clamp (values unused)
            float c0 = acc[mi][0][r] + bi0;
            float c1 = acc[mi][1][r] + bi1;
            if (Cinit) {
                c0 += Cinit[(size_t)grow * H + col0];
                c1 += Cinit[(size_t)grow * H + col1];
            }
            float x0 = fmaxf(c0, 0.f);
            float x1 = fmaxf(c1, 0.f);
            acc[mi][0][r] = x0; acc[mi][1][r] = x1;
            s[mi][r] = x0 + x1; q[mi][r] = x0 * x0 + x1 * x1;
        }
#pragma unroll
    for (int o = 1; o < 16; o <<= 1)
#pragma unroll
        for (int mi = 0; mi < 8; ++mi)
#pragma unroll
            for (int r = 0; r < 4; ++r) {
                s[mi][r] += __shfl_xor(s[mi][r], o);
                q[mi][r] += __shfl_xor(q[mi][r], o);
            }
    if (fr == 0) {
#pragma unroll
        for (int mi = 0; mi < 8; ++mi)
#pragma unroll
            for (int r = 0; r < 4; ++r) {
                int row = mi * 16 + fq * 4 + r;
                red[row][w] = s[mi][r];
                red[row][4 + w] = q[mi][r];
            }
    }
    __syncthreads();
#pragma unroll
    for (int mi = 0; mi < 8; ++mi)
#pragma unroll
        for (int r = 0; r < 4; ++r) {
            int rr = mi * 16 + fq * 4 + r;
            int grow = m0 + rr;
            if (grow < M) {
                float S = red[rr][0] + red[rr][1] + red[rr][2] + red[rr][3];
                float Q = red[rr][4] + red[rr][5] + red[rr][6] + red[rr][7];
                float mu = S * (1.f / 128.f);
                float var = Q * (1.f / 128.f) - mu * mu;
                float rs = rsqrtf(var + LEPS);
                out[(size_t)grow * H + col0] = (acc[mi][0][r] - mu) * rs * g0 + be0;
                out[(size_t)grow * H + col1] = (acc[mi][1][r] - mu) * rs * g1 + be1;
            }
        }
}

// ---------------- company: hcT = hc @ Wrel^T (exact fp32; feeds linear gather) -------
__global__ __launch_bounds__(128)
void comp_xform(const float* __restrict__ hc, const float* __restrict__ Wrel,
                float* __restrict__ out) {
    __shared__ float rowA[H];
    int n = blockIdx.x, h = threadIdx.x;
    rowA[h] = hc[(size_t)n * H + h];
    __syncthreads();
    float acc = 0.f;
    const float* wr = Wrel + (size_t)h * H;
#pragma unroll 4
    for (int k = 0; k < H; ++k) acc += rowA[k] * wr[k];
    out[(size_t)n * H + h] = acc;
}

// ---------------- company encoder (K=27) + fused ReLU+LN ----------------------------
__global__ __launch_bounds__(128)
void enc_comp_ln(const float* __restrict__ X, const float* __restrict__ W,
                 const float* __restrict__ bias, const float* __restrict__ g,
                 const float* __restrict__ be, float* __restrict__ out) {
    __shared__ float xr[DC];
    __shared__ float red[4];
    int n = blockIdx.x, h = threadIdx.x;
    if (h < DC) xr[h] = X[(size_t)n * DC + h];
    __syncthreads();
    float acc = bias[h];
    const float* w = W + (size_t)h * DC;
#pragma unroll
    for (int d = 0; d < DC; ++d) acc += xr[d] * w[d];
    float x = fmaxf(acc, 0.f);
    float s = x, q = x * x;
#pragma unroll
    for (int o = 32; o > 0; o >>= 1) { s += __shfl_xor(s, o); q += __shfl_xor(q, o); }
    if ((h & 63) == 0) { red[h >> 6] = s; red[2 + (h >> 6)] = q; }
    __syncthreads();
    float S = red[0] + red[1], Q = red[2] + red[3];
    float mu = S * (1.f / H);
    float var = Q * (1.f / H) - mu * mu;
    float rs = rsqrtf(var + LEPS);
    out[(size_t)n * H + h] = (x - mu) * rs * g[h] + be[h];
}

// ---------------- company combine + fused ReLU+LN ------------------------------------
__global__ __launch_bounds__(128)
void combine_c_ln(const float* __restrict__ msgc, const float* __restrict__ hc,
                  const float* __restrict__ Wrel, const float* __restrict__ Wroot,
                  const float* __restrict__ brel, const float* __restrict__ g,
                  const float* __restrict__ be, float* __restrict__ out) {
    __shared__ float rowA[H];
    __shared__ float rowB[H];
    __shared__ float red[4];
    int n = blockIdx.x, h = threadIdx.x;
    rowA[h] = msgc[(size_t)n * H + h];
    rowB[h] = hc[(size_t)n * H + h];
    __syncthreads();
    float acc = brel[h];
    const float* wr = Wrel + (size_t)h * H;
    const float* wo = Wroot + (size_t)h * H;
#pragma unroll 4
    for (int k = 0; k < H; ++k) acc += rowA[k] * wr[k] + rowB[k] * wo[k];
    float x = fmaxf(acc, 0.f);
    float s = x, q = x * x;
#pragma unroll
    for (int o = 32; o > 0; o >>= 1) { s += __shfl_xor(s, o); q += __shfl_xor(q, o); }
    if ((h & 63) == 0) { red[h >> 6] = s; red[2 + (h >> 6)] = q; }
    __syncthreads();
    float S = red[0] + red[1], Q = red[2] + red[3];
    float mu = S * (1.f / H);
    float var = Q * (1.f / H) - mu * mu;
    float rs = rsqrtf(var + LEPS);
    out[(size_t)n * H + h] = (x - mu) * rs * g[h] + be[h];
}

// ---------------- fused pooling + gated readout + classifier -------------------------
// NOTE: reference applies maximum(cnt_m,1) BEFORE the where test -> fallback is dead.
__global__ __launch_bounds__(128)
void pool_gate(const float* __restrict__ hf, const float* __restrict__ hc,
               const int* __restrict__ fbatch, const int* __restrict__ cbatch,
               const void* __restrict__ maskp, const int* __restrict__ flag,
               const float* __restrict__ Wg, const float* __restrict__ bg,
               const float* __restrict__ Wc, const float* __restrict__ bc,
               float* __restrict__ out) {
    __shared__ float red[4];
    int b = blockIdx.x, h = threadIdx.x;
    // fact mean pool
    int lo = lowerb(fbatch, NFACT, b), hi = lowerb(fbatch, NFACT, b + 1);
    float accf = 0.f;
    for (int r = lo; r < hi; ++r) accf += hf[(size_t)r * H + h];
    float fpv = accf / fmaxf((float)(hi - lo), 1.f);
    // masked comp pool
    lo = lowerb(cbatch, NCOMP, b); hi = lowerb(cbatch, NCOMP, b + 1);
    int isU8 = *flag;
    const unsigned char* m8 = (const unsigned char*)maskp;
    const int* m32 = (const int*)maskp;
    float accc = 0.f, cm = 0.f;
    for (int r = lo; r < hi; ++r) {
        float m = isU8 ? (m8[r] ? 1.f : 0.f) : (m32[r] ? 1.f : 0.f);
        accc += m * hc[(size_t)r * H + h];
        cm += m;
    }
    float cpv = accc / fmaxf(cm, 1.f);
    // gate
    float s = Wg[h] * fpv + Wg[H + h] * cpv;
#pragma unroll
    for (int o = 32; o > 0; o >>= 1) s += __shfl_xor(s, o);
    if ((h & 63) == 0) red[h >> 6] = s;
    __syncthreads();
    float alpha = sigmoidf(red[0] + red[1] + bg[0]);
    float v = (alpha * fpv + (1.f - alpha) * cpv) * Wc[h];
#pragma unroll
    for (int o = 32; o > 0; o >>= 1) v += __shfl_xor(v, o);
    if ((h & 63) == 0) red[2 + (h >> 6)] = v;
    __syncthreads();
    if (h == 0) out[b] = red[2] + red[3] + bc[0];
}

extern "C" void kernel_launch(void* const* d_in, const int* in_sizes, int n_in,
                              void* d_out, int out_size, void* d_ws, size_t ws_size,
                              hipStream_t stream) {
    const float* x_fact   = (const float*)d_in[0];
    const float* x_comp   = (const float*)d_in[1];
    const float* ea_fc    = (const float*)d_in[2];
    const float* ea_cf    = (const float*)d_in[3];
    const int*   src_fc   = (const int*)d_in[4];
    const int*   dst_fc   = (const int*)d_in[5];
    const int*   src_cf   = (const int*)d_in[6];
    const int*   dst_cf   = (const int*)d_in[7];
    const int*   fact_batch = (const int*)d_in[8];
    const int*   comp_batch = (const int*)d_in[9];
    const void*  pmask    = d_in[10];
    const float* W_in_f   = (const float*)d_in[11];
    const float* b_in_f   = (const float*)d_in[12];
    const float* g_in_f   = (const float*)d_in[13];
    const float* be_in_f  = (const float*)d_in[14];
    const float* W_in_c   = (const float*)d_in[15];
    const float* b_in_c   = (const float*)d_in[16];
    const float* g_in_c   = (const float*)d_in[17];
    const float* be_in_c  = (const float*)d_in[18];
    const float* w_mix    = (const float*)d_in[19];
    const float* b_mix    = (const float*)d_in[20];
    const float* Wrel_fc  = (const float*)d_in[21];
    const float* brel_fc  = (const float*)d_in[22];
    const float* Wroot_fc = (const float*)d_in[23];
    const float* Wrel_cf  = (const float*)d_in[24];
    const float* brel_cf  = (const float*)d_in[25];
    const float* Wroot_cf = (const float*)d_in[26];
    const float* g_post_f = (const float*)d_in[27];
    const float* b_post_f = (const float*)d_in[28];
    const float* g_post_c = (const float*)d_in[29];
    const float* b_post_c = (const float*)d_in[30];
    const float* W_gate   = (const float*)d_in[31];
    const float* b_gate   = (const float*)d_in[32];
    const float* W_cls    = (const float*)d_in[33];
    const float* b_cls    = (const float*)d_in[34];
    float* outp = (float*)d_out;
    (void)in_sizes; (void)n_in; (void)out_size; (void)ws_size;

    float* buf0  = (float*)d_ws;                        // hf ping  [NFACT,H]
    float* buf1  = buf0 + (size_t)NFACT * H;            // hf pong / G
    float* hc0   = buf1 + (size_t)NFACT * H;            // hc ping  [NCOMP,H]
    float* hc1   = hc0 + (size_t)NCOMP * H;             // hc pong
    float* msgc  = hc1 + (size_t)NCOMP * H;             // msg_c    [NCOMP,H]
    float* hcT   = msgc + (size_t)NCOMP * H;            // hc @ Wrel^T [NCOMP,H]
    float* swt_fc = hcT + (size_t)NCOMP * H;            // [E]
    float* swt_cf = swt_fc + (size_t)NEDGE;             // [E]
    int*   ssrc_fc = (int*)(swt_cf + (size_t)NEDGE);    // [E]
    int*   ssrc_cf = ssrc_fc + (size_t)NEDGE;           // [E]
    int*   off_fc  = ssrc_cf + (size_t)NEDGE;           // [NCOMP+1]
    int*   off_cf  = off_fc + (NCOMP + 1);              // [NFACT+1]
    int*   cur_fc  = off_cf + (NFACT + 1);              // [NCOMP]   (adjacent to cur_cf
    int*   cur_cf  = cur_fc + NCOMP;                    // [NFACT]    for single memset)
    int*   flag    = cur_cf + NFACT;

    uintptr_t pal = ((uintptr_t)(flag + 1) + 63) & ~(uintptr_t)63;
    __bf16* WencF = (__bf16*)pal;                       // 48*8192
    __bf16* Wr0F  = WencF + (size_t)48 * 8192;          // 4*8192
    __bf16* Wr1F  = Wr0F + (size_t)4 * 8192;

    mask_detect<<<1, 256, 0, stream>>>((const unsigned char*)pmask, NCOMP, flag);
    conv_all<<<(128 * DF + 2 * 128 * 128 + 255) / 256, 256, 0, stream>>>(
        W_in_f, Wroot_cf, Wroot_cf + (size_t)H * H, WencF, Wr0F, Wr1F);

    // ---- CSR build ----
    hipMemsetAsync(cur_fc, 0, (NCOMP + NFACT) * sizeof(int), stream);
    hist_all<<<(2 * NEDGE + 255) / 256, 256, 0, stream>>>(dst_fc, dst_cf, cur_fc, cur_cf);
    scan2<<<2, 1024, 0, stream>>>(cur_fc, off_fc, cur_cf, off_cf);
    scatter_all<<<(2 * NEDGE + 255) / 256, 256, 0, stream>>>(
        src_fc, dst_fc, ea_fc, src_cf, dst_cf, ea_cf, w_mix, b_mix,
        cur_fc, cur_cf, ssrc_fc, swt_fc, ssrc_cf, swt_cf);

    // ---- encoders ----
    gemm128_mfma<<<(NFACT + 127) / 128, 256, 0, stream>>>(
        x_fact, WencF, nullptr, b_in_f, g_in_f, be_in_f, buf0, NFACT, DF);
    enc_comp_ln<<<NCOMP, 128, 0, stream>>>(x_comp, W_in_c, b_in_c, g_in_c, be_in_c, hc0);

    float* hf = buf0; float* hfN = buf1;
    float* hc = hc0;  float* hcN = hc1;

    for (int l = 0; l < 2; ++l) {
        // fact side: gather in Wrel-transformed space (linearity), root GEMM K=128
        comp_xform<<<NCOMP, 128, 0, stream>>>(hc, Wrel_cf + (size_t)l * H * H, hcT);
        gather_fact<<<(NFACT + 1) / 2, 256, 0, stream>>>(off_cf, ssrc_cf, swt_cf, hcT, hfN);
        gather_comp<<<NCOMP, 512, 0, stream>>>(off_fc, ssrc_fc, swt_fc, hf, msgc);
        gemm128_mfma<<<(NFACT + 127) / 128, 256, 0, stream>>>(
            hf, (l == 0) ? Wr0F : Wr1F, hfN, brel_cf + (size_t)l * H,
            g_post_f, b_post_f, hfN, NFACT, H);
        combine_c_ln<<<NCOMP, 128, 0, stream>>>(msgc, hc,
            Wrel_fc + (size_t)l * H * H, Wroot_fc + (size_t)l * H * H,
            brel_fc + (size_t)l * H, g_post_c, b_post_c, hcN);
        float* t = hf; hf = hfN; hfN = t;
        t = hc; hc = hcN; hcN = t;
    }

    pool_gate<<<BGRAPH, 128, 0, stream>>>(hf, hc, fact_batch, comp_batch, pmask, flag,
                                          W_gate, b_gate, W_cls, b_cls, outp);
}